// Round 4
// baseline (133.466 us; speedup 1.0000x reference)
//
#include <hip/hip_runtime.h>

// CRF-RNN mean-field, 2 iterations, N=8192 (32x16x16), C=4.
// Spatial attention is exactly separable (regular-grid Gaussian) -> 3 dense 1-D convs.
// Bilateral attention stays N^2, split-K over j for occupancy.
// Per iteration:
//   conv_dw   (32 blk):  softmax(q) -> sm; conv along D then W -> tmp
//   bilat_pass1 (2048 blk): N^2 bilateral numerators -> part[kSplit][N][4]
//   reduce_h (128 blk):  split-K sum (coalesced) + conv along H -> blP, spP
//   finish   (32 blk):   normalize (denom == channel-sum), 4x4 matmuls, + unaries

#define HH 32
#define WW 16
#define DDD 16
#define NN (HH * WW * DDD)    // 8192
#define TILE 64               // j-records per LDS tile in bilat_pass1
#define L2E 1.4426950408889634f
#define C18 (L2E / 18.0f)     // exp(-d^2/(2*3^2)) == exp2(-d^2*C18)

#if __has_builtin(__builtin_amdgcn_exp2f)
#define EXP2(x) __builtin_amdgcn_exp2f(x)
#else
#define EXP2(x) exp2f(x)
#endif

// bilateral features pre-scaled by sqrt(log2 e) so exp(logit) == exp2(scaled logit)
__device__ __forceinline__ void bilat_feats(int n, const float* __restrict__ rgb,
                                            float fb[6], float& nhb)
{
    const float SQL2E = 1.2011224087864498f;  // sqrt(log2(e))
    int h = n >> 8;
    int r = n & 255;
    int w = r >> 4;
    int d = r & 15;
    const float sb = SQL2E / 8.0f;   // THETA_ALPHA
    const float sc = SQL2E / 0.5f;   // THETA_BETA
    fb[0] = (float)(h + 1) * sb;
    fb[1] = (float)(w + 1) * sb;
    fb[2] = (float)(d + 1) * sb;
    fb[3] = rgb[3 * n + 0] * sc;
    fb[4] = rgb[3 * n + 1] * sc;
    fb[5] = rgb[3 * n + 2] * sc;
    nhb = -0.5f * (fb[0] * fb[0] + fb[1] * fb[1] + fb[2] * fb[2] +
                   fb[3] * fb[3] + fb[4] * fb[4] + fb[5] * fb[5]);
}

// Per h-slab: softmax(q) -> sm (global), then 1-D Gaussian conv along D then W.
__global__ __launch_bounds__(256) void conv_dw(
    const float* __restrict__ qin,   // [N][4]
    float* __restrict__ smout,       // [N][4]
    float* __restrict__ tmp)         // [N][4] d,w-convolved sm
{
    int h = blockIdx.x;
    int s = threadIdx.x;             // s = w*16 + d
    int i = h * 256 + s;

    float4 q = *((const float4*)(qin + 4 * i));
    float m = fmaxf(fmaxf(q.x, q.y), fmaxf(q.z, q.w));
    float e0 = EXP2((q.x - m) * L2E), e1 = EXP2((q.y - m) * L2E);
    float e2 = EXP2((q.z - m) * L2E), e3 = EXP2((q.w - m) * L2E);
    float rs = 1.0f / (e0 + e1 + e2 + e3);
    float4 sm = make_float4(e0 * rs, e1 * rs, e2 * rs, e3 * rs);
    *((float4*)(smout + 4 * i)) = sm;

    __shared__ float A[256][4];
    __shared__ float B[256][4];
    *((float4*)A[s]) = sm;
    __syncthreads();

    int w = s >> 4, d = s & 15;
    float t0 = 0, t1 = 0, t2 = 0, t3 = 0;
    #pragma unroll
    for (int dp = 0; dp < DDD; ++dp) {
        float dd = (float)(d - dp);
        float k = EXP2(-dd * dd * C18);
        const float4 v = *((const float4*)A[w * 16 + dp]);
        t0 = fmaf(k, v.x, t0); t1 = fmaf(k, v.y, t1);
        t2 = fmaf(k, v.z, t2); t3 = fmaf(k, v.w, t3);
    }
    *((float4*)B[s]) = make_float4(t0, t1, t2, t3);
    __syncthreads();

    float u0 = 0, u1 = 0, u2 = 0, u3 = 0;
    #pragma unroll
    for (int wp = 0; wp < WW; ++wp) {
        float dw = (float)(w - wp);
        float k = EXP2(-dw * dw * C18);
        const float4 v = *((const float4*)B[wp * 16 + d]);
        u0 = fmaf(k, v.x, u0); u1 = fmaf(k, v.y, u1);
        u2 = fmaf(k, v.z, u2); u3 = fmaf(k, v.w, u3);
    }
    *((float4*)(tmp + 4 * i)) = make_float4(u0, u1, u2, u3);
}

// N^2 bilateral numerators, 2 i-rows per thread, split-K over j.
__global__ __launch_bounds__(256) void bilat_pass1(
    const float* __restrict__ sm,    // [N][4]
    const float* __restrict__ rgb,   // [N][3]
    float* __restrict__ part,        // [kSplit][N][4]
    int kSplit)
{
    const int NBI2 = NN / 512;       // 16 i-tiles (512 i per block)
    int kc = blockIdx.x / NBI2;
    int ib = blockIdx.x - kc * NBI2;
    int tid = threadIdx.x;
    int i0 = ib * 512 + tid;
    int i1 = i0 + 256;
    int JC = NN / kSplit;
    int j0 = kc * JC;

    float fA[6], fB[6], nA, nB;
    bilat_feats(i0, rgb, fA, nA);
    bilat_feats(i1, rgb, fB, nB);

    // 12-float (48B) records
    __shared__ float recs[TILE][12];

    float a0 = 0, a1 = 0, a2 = 0, a3 = 0;
    float b0 = 0, b1 = 0, b2 = 0, b3 = 0;

    for (int jt = 0; jt < JC; jt += TILE) {
        int tc = JC - jt; if (tc > TILE) tc = TILE;
        __syncthreads();
        if (tid < tc) {
            int j = j0 + jt + tid;
            float fj[6], nj;
            bilat_feats(j, rgb, fj, nj);
            float4 s = *((const float4*)(sm + 4 * j));
            *((float4*)&recs[tid][0]) = make_float4(fj[0], fj[1], fj[2], fj[3]);
            *((float4*)&recs[tid][4]) = make_float4(fj[4], fj[5], nj, 0.0f);
            *((float4*)&recs[tid][8]) = s;
        }
        __syncthreads();

        #pragma unroll 8
        for (int jj = 0; jj < tc; ++jj) {
            const float4 r0 = *((const float4*)&recs[jj][0]);
            const float4 r1 = *((const float4*)&recs[jj][4]);
            const float4 s  = *((const float4*)&recs[jj][8]);
            float gA = nA + r1.z;
            gA = fmaf(fA[0], r0.x, gA);
            gA = fmaf(fA[1], r0.y, gA);
            gA = fmaf(fA[2], r0.z, gA);
            gA = fmaf(fA[3], r0.w, gA);
            gA = fmaf(fA[4], r1.x, gA);
            gA = fmaf(fA[5], r1.y, gA);
            float gB = nB + r1.z;
            gB = fmaf(fB[0], r0.x, gB);
            gB = fmaf(fB[1], r0.y, gB);
            gB = fmaf(fB[2], r0.z, gB);
            gB = fmaf(fB[3], r0.w, gB);
            gB = fmaf(fB[4], r1.x, gB);
            gB = fmaf(fB[5], r1.y, gB);
            float wA = EXP2(gA);
            float wB = EXP2(gB);
            a0 = fmaf(wA, s.x, a0); a1 = fmaf(wA, s.y, a1);
            a2 = fmaf(wA, s.z, a2); a3 = fmaf(wA, s.w, a3);
            b0 = fmaf(wB, s.x, b0); b1 = fmaf(wB, s.y, b1);
            b2 = fmaf(wB, s.z, b2); b3 = fmaf(wB, s.w, b3);
        }
    }

    float4* p = (float4*)(part + (size_t)kc * NN * 4);
    p[i0] = make_float4(a0, a1, a2, a3);
    p[i1] = make_float4(b0, b1, b2, b3);
}

// One thread per (i,c): coalesced split-K sum of bilateral partials + conv along H.
__global__ __launch_bounds__(256) void reduce_h(
    const float* __restrict__ part, int kSplit,
    const float* __restrict__ tmp,   // [N][4] d,w-convolved sm
    float* __restrict__ blP,         // [N][4] bilateral numerators
    float* __restrict__ spP)         // [N][4] spatial numerators
{
    int idx = blockIdx.x * 256 + threadIdx.x;   // (i*4 + c), 32768 total
    int i = idx >> 2;
    int h = i >> 8;
    int sc = idx & 1023;                        // s*4 + c within the h-slab

    float bl = 0.0f;
    for (int kc = 0; kc < kSplit; ++kc)
        bl += part[(size_t)kc * (NN * 4) + idx];

    float sp = 0.0f;
    #pragma unroll
    for (int hp = 0; hp < HH; ++hp) {
        float dh = (float)(h - hp);
        float k = EXP2(-dh * dh * C18);
        sp = fmaf(k, tmp[hp * 1024 + sc], sp);
    }
    blP[idx] = bl;
    spP[idx] = sp;
}

// Normalize (denominator == channel-sum since sum_c sm == 1), 4x4 matmuls, + unary.
__global__ __launch_bounds__(256) void finish(
    const float* __restrict__ blP, const float* __restrict__ spP,
    const float* __restrict__ u,
    const float* __restrict__ sk, const float* __restrict__ bk,
    const float* __restrict__ cm,
    float* __restrict__ qout)
{
    int i = blockIdx.x * 256 + threadIdx.x;
    float4 b4 = *((const float4*)(blP + 4 * i));
    float4 s4 = *((const float4*)(spP + 4 * i));
    float rb = 1.0f / (b4.x + b4.y + b4.z + b4.w);
    float rs = 1.0f / (s4.x + s4.y + s4.z + s4.w);
    float bo[4] = { b4.x * rb, b4.y * rb, b4.z * rb, b4.w * rb };
    float so[4] = { s4.x * rs, s4.y * rs, s4.z * rs, s4.w * rs };

    float msg[4];
    #pragma unroll
    for (int c = 0; c < 4; ++c) {
        float m = 0.0f;
        #pragma unroll
        for (int d = 0; d < 4; ++d)
            m += sk[c * 4 + d] * so[d] + bk[c * 4 + d] * bo[d];
        msg[c] = m;
    }
    #pragma unroll
    for (int c = 0; c < 4; ++c) {
        float pw = 0.0f;
        #pragma unroll
        for (int d = 0; d < 4; ++d) pw += cm[c * 4 + d] * msg[d];
        qout[4 * i + c] = u[4 * i + c] + pw;
    }
}

extern "C" void kernel_launch(void* const* d_in, const int* in_sizes, int n_in,
                              void* d_out, int out_size, void* d_ws, size_t ws_size,
                              hipStream_t stream)
{
    const float* u   = (const float*)d_in[0];
    const float* rgb = (const float*)d_in[1];
    const float* sk  = (const float*)d_in[2];
    const float* bk  = (const float*)d_in[3];
    const float* cm  = (const float*)d_in[4];
    float* out = (float*)d_out;

    // workspace: part[kSplit][N][4] | sm | tmp | bl | sp | qbuf (each [N][4])
    int kSplit = 128;
    while (kSplit > 1 &&
           ((size_t)kSplit * NN * 4 + 5 * (size_t)NN * 4) * sizeof(float) > ws_size)
        kSplit >>= 1;

    float* part = (float*)d_ws;
    float* smP  = part + (size_t)kSplit * NN * 4;
    float* tmpP = smP  + (size_t)NN * 4;
    float* blP  = tmpP + (size_t)NN * 4;
    float* spP  = blP  + (size_t)NN * 4;
    float* qbuf = spP  + (size_t)NN * 4;

    dim3 blk(256);
    dim3 gS(HH);                       // 32 blocks
    dim3 g1((NN / 512) * kSplit);      // 16 * kSplit blocks
    dim3 gR(NN * 4 / 256);             // 128 blocks

    // iteration 1 (q = u)
    conv_dw<<<gS, blk, 0, stream>>>(u, smP, tmpP);
    bilat_pass1<<<g1, blk, 0, stream>>>(smP, rgb, part, kSplit);
    reduce_h<<<gR, blk, 0, stream>>>(part, kSplit, tmpP, blP, spP);
    finish<<<gS, blk, 0, stream>>>(blP, spP, u, sk, bk, cm, qbuf);
    // iteration 2
    conv_dw<<<gS, blk, 0, stream>>>(qbuf, smP, tmpP);
    bilat_pass1<<<g1, blk, 0, stream>>>(smP, rgb, part, kSplit);
    reduce_h<<<gR, blk, 0, stream>>>(part, kSplit, tmpP, blP, spP);
    finish<<<gS, blk, 0, stream>>>(blP, spP, u, sk, bk, cm, out);
}

// Round 5
// 66.668 us; speedup vs baseline: 2.0020x; 2.0020x over previous
//
#include <hip/hip_runtime.h>

// CRF-RNN mean-field, 2 iterations, N=8192 (32x16x16), C=4.
// Spatial attention: exactly separable (regular-grid Gaussian) -> 3 dense 1-D convs.
// Bilateral attention: N^2 with compile-time split-K (KS) over j.
// Per iteration (3 dispatches):
//   conv_dw       (32 blk): softmax(q); conv along D then W -> tmp
//   bilat_pass1 (1024 blk): 4 i-rows/thread, delta-logit, fused j-softmax -> part
//   reduce_finish(512 blk): wave-parallel split-K sum + h-conv + normalize
//                           + 4x4 matmuls + unary add -> q_next

#define HH 32
#define WW 16
#define DDD 16
#define NN (HH * WW * DDD)    // 8192
#define KS 128                // split-K over j (compile-time!)
#define JC (NN / KS)          // 64 j per block
#define L2E 1.4426950408889634f
#define C18 (L2E / 18.0f)     // exp(-d^2/(2*3^2)) == exp2(-d^2*C18)
#define SQL2E 1.2011224087864498f   // sqrt(log2 e): feats pre-scaled so exp==exp2
#define SB (SQL2E / 8.0f)     // THETA_ALPHA
#define SC (SQL2E / 0.5f)     // THETA_BETA

#if __has_builtin(__builtin_amdgcn_exp2f)
#define EXP2(x) __builtin_amdgcn_exp2f(x)
#else
#define EXP2(x) exp2f(x)
#endif

// Per h-slab: softmax(q) then 1-D Gaussian conv along D then W -> tmp.
__global__ __launch_bounds__(256) void conv_dw(
    const float* __restrict__ qin,   // [N][4]
    float* __restrict__ tmp)         // [N][4] d,w-convolved softmax
{
    int h = blockIdx.x;
    int s = threadIdx.x;             // s = w*16 + d
    int i = h * 256 + s;

    float4 q = *((const float4*)(qin + 4 * i));
    float m = fmaxf(fmaxf(q.x, q.y), fmaxf(q.z, q.w));
    float e0 = EXP2((q.x - m) * L2E), e1 = EXP2((q.y - m) * L2E);
    float e2 = EXP2((q.z - m) * L2E), e3 = EXP2((q.w - m) * L2E);
    float rs = 1.0f / (e0 + e1 + e2 + e3);

    __shared__ float A[256][4];
    __shared__ float B[256][4];
    *((float4*)A[s]) = make_float4(e0 * rs, e1 * rs, e2 * rs, e3 * rs);
    __syncthreads();

    int w = s >> 4, d = s & 15;
    float t0 = 0, t1 = 0, t2 = 0, t3 = 0;
    #pragma unroll
    for (int dp = 0; dp < DDD; ++dp) {
        float dd = (float)(d - dp);
        float k = EXP2(-dd * dd * C18);
        const float4 v = *((const float4*)A[w * 16 + dp]);
        t0 = fmaf(k, v.x, t0); t1 = fmaf(k, v.y, t1);
        t2 = fmaf(k, v.z, t2); t3 = fmaf(k, v.w, t3);
    }
    *((float4*)B[s]) = make_float4(t0, t1, t2, t3);
    __syncthreads();

    float u0 = 0, u1 = 0, u2 = 0, u3 = 0;
    #pragma unroll
    for (int wp = 0; wp < WW; ++wp) {
        float dw = (float)(w - wp);
        float k = EXP2(-dw * dw * C18);
        const float4 v = *((const float4*)B[wp * 16 + d]);
        u0 = fmaf(k, v.x, u0); u1 = fmaf(k, v.y, u1);
        u2 = fmaf(k, v.z, u2); u3 = fmaf(k, v.w, u3);
    }
    *((float4*)(tmp + 4 * i)) = make_float4(u0, u1, u2, u3);
}

// N^2 bilateral numerators. Block = (i-tile of 1024 rows: 4 rows/thread) x (64 j).
// Rows of one thread differ only in h (+k) and rgb -> delta-logit (5 FMA/extra row).
__global__ __launch_bounds__(256) void bilat_pass1(
    const float* __restrict__ qin,   // [N][4] (softmax fused here for j-records)
    const float* __restrict__ rgb,   // [N][3]
    float* __restrict__ part)        // [KS][N*4]
{
    int ib = blockIdx.x >> 7;        // 8 i-tiles
    int kc = blockIdx.x & (KS - 1);  // 128 j-chunks
    int tid = threadIdx.x;
    int i0 = ib * 1024 + tid;        // rows: i0 + k*256, k=0..3
    int j0 = kc * JC;

    // i-side features (wave-uniform h per row; w,d from tid)
    float fw = (float)(((tid >> 4) & 15) + 1) * SB;
    float fd = (float)((tid & 15) + 1) * SB;
    int hb = i0 >> 8;                // = ib*4
    float fh[4], cr[4][3], nn[4];
    #pragma unroll
    for (int k = 0; k < 4; ++k) {
        int ik = i0 + k * 256;
        fh[k] = (float)(hb + k + 1) * SB;
        cr[k][0] = rgb[3 * ik + 0] * SC;
        cr[k][1] = rgb[3 * ik + 1] * SC;
        cr[k][2] = rgb[3 * ik + 2] * SC;
        nn[k] = -0.5f * (fh[k] * fh[k] + fw * fw + fd * fd +
                         cr[k][0] * cr[k][0] + cr[k][1] * cr[k][1] + cr[k][2] * cr[k][2]);
    }
    float dfh[3], dc[3][3], dn[3];
    #pragma unroll
    for (int k = 0; k < 3; ++k) {
        dfh[k] = fh[k + 1] - fh[0];
        dc[k][0] = cr[k + 1][0] - cr[0][0];
        dc[k][1] = cr[k + 1][1] - cr[0][1];
        dc[k][2] = cr[k + 1][2] - cr[0][2];
        dn[k] = nn[k + 1] - nn[0];
    }

    // stage JC=64 j-records: {fjh,fjw,fjd,fjc0 | fjc1,fjc2,nj,0 | s0,s1,s2,s3}
    __shared__ float recs[JC][12];
    if (tid < JC) {
        int j = j0 + tid;
        int jh = j >> 8, jr = j & 255;
        float gh = (float)(jh + 1) * SB;
        float gw = (float)((jr >> 4) + 1) * SB;
        float gd = (float)((jr & 15) + 1) * SB;
        float c0 = rgb[3 * j + 0] * SC;
        float c1 = rgb[3 * j + 1] * SC;
        float c2 = rgb[3 * j + 2] * SC;
        float nj = -0.5f * (gh * gh + gw * gw + gd * gd + c0 * c0 + c1 * c1 + c2 * c2);
        float4 q = *((const float4*)(qin + 4 * j));
        float m = fmaxf(fmaxf(q.x, q.y), fmaxf(q.z, q.w));
        float e0 = EXP2((q.x - m) * L2E), e1 = EXP2((q.y - m) * L2E);
        float e2 = EXP2((q.z - m) * L2E), e3 = EXP2((q.w - m) * L2E);
        float rs = 1.0f / (e0 + e1 + e2 + e3);
        *((float4*)&recs[tid][0]) = make_float4(gh, gw, gd, c0);
        *((float4*)&recs[tid][4]) = make_float4(c1, c2, nj, 0.0f);
        *((float4*)&recs[tid][8]) = make_float4(e0 * rs, e1 * rs, e2 * rs, e3 * rs);
    }
    __syncthreads();

    float acc[4][4];
    #pragma unroll
    for (int k = 0; k < 4; ++k)
        #pragma unroll
        for (int c = 0; c < 4; ++c) acc[k][c] = 0.0f;

    #pragma unroll 8
    for (int jj = 0; jj < JC; ++jj) {
        const float4 r0 = *((const float4*)&recs[jj][0]);
        const float4 r1 = *((const float4*)&recs[jj][4]);
        const float4 s  = *((const float4*)&recs[jj][8]);
        float g0 = nn[0] + r1.z;
        g0 = fmaf(fh[0],    r0.x, g0);
        g0 = fmaf(fw,       r0.y, g0);
        g0 = fmaf(fd,       r0.z, g0);
        g0 = fmaf(cr[0][0], r0.w, g0);
        g0 = fmaf(cr[0][1], r1.x, g0);
        g0 = fmaf(cr[0][2], r1.y, g0);
        float wk[4];
        wk[0] = EXP2(g0);
        #pragma unroll
        for (int k = 0; k < 3; ++k) {
            float g = fmaf(dfh[k], r0.x, g0 + dn[k]);
            g = fmaf(dc[k][0], r0.w, g);
            g = fmaf(dc[k][1], r1.x, g);
            g = fmaf(dc[k][2], r1.y, g);
            wk[k + 1] = EXP2(g);
        }
        #pragma unroll
        for (int k = 0; k < 4; ++k) {
            acc[k][0] = fmaf(wk[k], s.x, acc[k][0]);
            acc[k][1] = fmaf(wk[k], s.y, acc[k][1]);
            acc[k][2] = fmaf(wk[k], s.z, acc[k][2]);
            acc[k][3] = fmaf(wk[k], s.w, acc[k][3]);
        }
    }

    float* p = part + (size_t)kc * (NN * 4);
    #pragma unroll
    for (int k = 0; k < 4; ++k)
        *((float4*)(p + (size_t)(i0 + k * 256) * 4)) =
            make_float4(acc[k][0], acc[k][1], acc[k][2], acc[k][3]);
}

// 512 blocks x 256 thr. Block owns 64 idx (= 16 i x 4 c).
// Wave q: sums part slices [q*32, q*32+32) (coalesced, unrolled) and 8 hp of h-conv.
// LDS combine; threads 0..15 finish: normalize + 4x4 matmuls + unary add.
__global__ __launch_bounds__(256) void reduce_finish(
    const float* __restrict__ part,  // [KS][N*4]
    const float* __restrict__ tmp,   // [N][4] d,w-convolved softmax
    const float* __restrict__ u,
    const float* __restrict__ sk, const float* __restrict__ bk,
    const float* __restrict__ cm,
    float* __restrict__ qout)
{
    int tid = threadIdx.x;
    int q = tid >> 6;                // wave 0..3
    int lane = tid & 63;
    int idx = blockIdx.x * 64 + lane;

    float bl = 0.0f;
    #pragma unroll
    for (int k = 0; k < KS / 4; ++k)
        bl += part[(size_t)(q * (KS / 4) + k) * (NN * 4) + idx];

    int i = idx >> 2;
    int h = i >> 8;
    int scid = idx & 1023;
    float sp = 0.0f;
    #pragma unroll
    for (int k = 0; k < 8; ++k) {
        int hp = q * 8 + k;
        float dh = (float)(h - hp);
        float kk = EXP2(-dh * dh * C18);
        sp = fmaf(kk, tmp[hp * 1024 + scid], sp);
    }

    __shared__ float Lb[4][64];
    __shared__ float Ls[4][64];
    Lb[q][lane] = bl;
    Ls[q][lane] = sp;
    __syncthreads();

    if (tid < 16) {
        float b4[4], s4[4];
        #pragma unroll
        for (int c = 0; c < 4; ++c) {
            int l = tid * 4 + c;
            b4[c] = Lb[0][l] + Lb[1][l] + Lb[2][l] + Lb[3][l];
            s4[c] = Ls[0][l] + Ls[1][l] + Ls[2][l] + Ls[3][l];
        }
        float rb = 1.0f / (b4[0] + b4[1] + b4[2] + b4[3]);
        float rs = 1.0f / (s4[0] + s4[1] + s4[2] + s4[3]);
        float bo[4], so[4];
        #pragma unroll
        for (int c = 0; c < 4; ++c) { bo[c] = b4[c] * rb; so[c] = s4[c] * rs; }
        float msg[4];
        #pragma unroll
        for (int c = 0; c < 4; ++c) {
            float m = 0.0f;
            #pragma unroll
            for (int d = 0; d < 4; ++d)
                m += sk[c * 4 + d] * so[d] + bk[c * 4 + d] * bo[d];
            msg[c] = m;
        }
        int ig = blockIdx.x * 16 + tid;
        #pragma unroll
        for (int c = 0; c < 4; ++c) {
            float pw = 0.0f;
            #pragma unroll
            for (int d = 0; d < 4; ++d) pw += cm[c * 4 + d] * msg[d];
            qout[4 * ig + c] = u[4 * ig + c] + pw;
        }
    }
}

extern "C" void kernel_launch(void* const* d_in, const int* in_sizes, int n_in,
                              void* d_out, int out_size, void* d_ws, size_t ws_size,
                              hipStream_t stream)
{
    const float* u   = (const float*)d_in[0];
    const float* rgb = (const float*)d_in[1];
    const float* sk  = (const float*)d_in[2];
    const float* bk  = (const float*)d_in[3];
    const float* cm  = (const float*)d_in[4];
    float* out = (float*)d_out;

    // workspace: part[KS][N*4] (16 MB) | tmp[N][4] | qbuf[N][4]
    float* part = (float*)d_ws;
    float* tmpP = part + (size_t)KS * NN * 4;
    float* qbuf = tmpP + (size_t)NN * 4;

    dim3 blk(256);
    dim3 gC(HH);                 // 32
    dim3 gB(8 * KS);             // 1024
    dim3 gR(NN * 4 / 64);        // 512

    // iteration 1 (q = u)
    conv_dw<<<gC, blk, 0, stream>>>(u, tmpP);
    bilat_pass1<<<gB, blk, 0, stream>>>(u, rgb, part);
    reduce_finish<<<gR, blk, 0, stream>>>(part, tmpP, u, sk, bk, cm, qbuf);
    // iteration 2
    conv_dw<<<gC, blk, 0, stream>>>(qbuf, tmpP);
    bilat_pass1<<<gB, blk, 0, stream>>>(qbuf, rgb, part);
    reduce_finish<<<gR, blk, 0, stream>>>(part, tmpP, u, sk, bk, cm, out);
}

// Round 6
// 62.355 us; speedup vs baseline: 2.1404x; 1.0692x over previous
//
#include <hip/hip_runtime.h>

// CRF-RNN mean-field, 2 iterations, N=8192 (32x16x16), C=4.
// Spatial attention: exactly separable (regular-grid Gaussian) -> 3 dense 1-D convs.
// Bilateral attention: N^2 with compile-time split-K (KS) over j.
// Per iteration (2 dispatches):
//   fused_bilat_conv (2048+32 blk): blocks <2048: bilateral numerators
//       (2 i-rows/thread, delta-logit, fused j-softmax) -> part;
//       blocks >=2048: softmax + spatial conv along D,W -> tmp.
//   reduce_finish (512 blk): wave-parallel split-K sum + h-conv + normalize
//       + 4x4 matmuls + unary add -> q_next.

#define HH 32
#define WW 16
#define DDD 16
#define NN (HH * WW * DDD)    // 8192
#define KS 128                // split-K over j (compile-time)
#define JC (NN / KS)          // 64 j per block
#define GB 2048               // bilat blocks (16 i-tiles x KS)
#define L2E 1.4426950408889634f
#define C18 (L2E / 18.0f)     // exp(-d^2/(2*3^2)) == exp2(-d^2*C18)
#define SQL2E 1.2011224087864498f   // sqrt(log2 e): feats pre-scaled so exp==exp2
#define SB (SQL2E / 8.0f)     // THETA_ALPHA
#define SC (SQL2E / 0.5f)     // THETA_BETA

#if __has_builtin(__builtin_amdgcn_exp2f)
#define EXP2(x) __builtin_amdgcn_exp2f(x)
#else
#define EXP2(x) exp2f(x)
#endif

__global__ __launch_bounds__(256, 8) void fused_bilat_conv(
    const float* __restrict__ qin,   // [N][4]
    const float* __restrict__ rgb,   // [N][3]
    float* __restrict__ part,        // [KS][N*4]
    float* __restrict__ tmp)         // [N][4] d,w-convolved softmax
{
    __shared__ float lds[2048];      // bilat: recs[64][12]; conv: A[1024]|B[1024]
    int tid = threadIdx.x;

    if (blockIdx.x < GB) {
        // ---------------- bilateral N^2 ----------------
        int ib = blockIdx.x >> 7;        // 16 i-tiles (512 rows each)
        int kc = blockIdx.x & (KS - 1);  // 128 j-chunks
        int i0 = ib * 512 + tid;         // rows: i0, i0+256
        int i1 = i0 + 256;
        int j0 = kc * JC;

        // i-side features: rows share w,d; h differs by exactly 1 (dfh = SB).
        float fw = (float)(((tid >> 4) & 15) + 1) * SB;
        float fd = (float)((tid & 15) + 1) * SB;
        int hb = ib * 2;
        float fh = (float)(hb + 1) * SB;
        float c00 = rgb[3 * i0 + 0] * SC;
        float c01 = rgb[3 * i0 + 1] * SC;
        float c02 = rgb[3 * i0 + 2] * SC;
        float c10 = rgb[3 * i1 + 0] * SC;
        float c11 = rgb[3 * i1 + 1] * SC;
        float c12 = rgb[3 * i1 + 2] * SC;
        float fh1 = fh + SB;
        float nn0 = -0.5f * (fh * fh + fw * fw + fd * fd +
                             c00 * c00 + c01 * c01 + c02 * c02);
        float nn1 = -0.5f * (fh1 * fh1 + fw * fw + fd * fd +
                             c10 * c10 + c11 * c11 + c12 * c12);
        float dn = nn1 - nn0;
        float dc0 = c10 - c00, dc1 = c11 - c01, dc2 = c12 - c02;

        // stage JC=64 j-records {gh,gw,gd,c0 | c1,c2,nj,0 | s0,s1,s2,s3}
        float (*recs)[12] = (float(*)[12])lds;
        if (tid < JC) {
            int j = j0 + tid;
            int jh = j >> 8, jr = j & 255;
            float gh = (float)(jh + 1) * SB;
            float gw = (float)((jr >> 4) + 1) * SB;
            float gd = (float)((jr & 15) + 1) * SB;
            float b0 = rgb[3 * j + 0] * SC;
            float b1 = rgb[3 * j + 1] * SC;
            float b2 = rgb[3 * j + 2] * SC;
            float nj = -0.5f * (gh * gh + gw * gw + gd * gd +
                                b0 * b0 + b1 * b1 + b2 * b2);
            float4 q = *((const float4*)(qin + 4 * j));
            float m = fmaxf(fmaxf(q.x, q.y), fmaxf(q.z, q.w));
            float e0 = EXP2((q.x - m) * L2E), e1 = EXP2((q.y - m) * L2E);
            float e2 = EXP2((q.z - m) * L2E), e3 = EXP2((q.w - m) * L2E);
            float rs = 1.0f / (e0 + e1 + e2 + e3);
            *((float4*)&recs[tid][0]) = make_float4(gh, gw, gd, b0);
            *((float4*)&recs[tid][4]) = make_float4(b1, b2, nj, 0.0f);
            *((float4*)&recs[tid][8]) = make_float4(e0 * rs, e1 * rs, e2 * rs, e3 * rs);
        }
        __syncthreads();

        float a0 = 0, a1 = 0, a2 = 0, a3 = 0;
        float b0a = 0, b1a = 0, b2a = 0, b3a = 0;

        #pragma unroll 4
        for (int jj = 0; jj < JC; ++jj) {
            const float4 r0 = *((const float4*)&recs[jj][0]);
            const float4 r1 = *((const float4*)&recs[jj][4]);
            const float4 s  = *((const float4*)&recs[jj][8]);
            float g0 = nn0 + r1.z;
            g0 = fmaf(fh,  r0.x, g0);
            g0 = fmaf(fw,  r0.y, g0);
            g0 = fmaf(fd,  r0.z, g0);
            g0 = fmaf(c00, r0.w, g0);
            g0 = fmaf(c01, r1.x, g0);
            g0 = fmaf(c02, r1.y, g0);
            float g1 = g0 + dn;
            g1 = fmaf(SB,  r0.x, g1);
            g1 = fmaf(dc0, r0.w, g1);
            g1 = fmaf(dc1, r1.x, g1);
            g1 = fmaf(dc2, r1.y, g1);
            float w0 = EXP2(g0);
            float w1 = EXP2(g1);
            a0  = fmaf(w0, s.x, a0);  a1  = fmaf(w0, s.y, a1);
            a2  = fmaf(w0, s.z, a2);  a3  = fmaf(w0, s.w, a3);
            b0a = fmaf(w1, s.x, b0a); b1a = fmaf(w1, s.y, b1a);
            b2a = fmaf(w1, s.z, b2a); b3a = fmaf(w1, s.w, b3a);
        }

        float* p = part + (size_t)kc * (NN * 4);
        *((float4*)(p + (size_t)i0 * 4)) = make_float4(a0, a1, a2, a3);
        *((float4*)(p + (size_t)i1 * 4)) = make_float4(b0a, b1a, b2a, b3a);
    } else {
        // ---------------- spatial: softmax + conv D, conv W ----------------
        int h = blockIdx.x - GB;
        int s = tid;                 // s = w*16 + d
        int i = h * 256 + s;

        float4 q = *((const float4*)(qin + 4 * i));
        float m = fmaxf(fmaxf(q.x, q.y), fmaxf(q.z, q.w));
        float e0 = EXP2((q.x - m) * L2E), e1 = EXP2((q.y - m) * L2E);
        float e2 = EXP2((q.z - m) * L2E), e3 = EXP2((q.w - m) * L2E);
        float rs = 1.0f / (e0 + e1 + e2 + e3);

        float* A = lds;              // [256][4]
        float* B = lds + 1024;       // [256][4]
        *((float4*)(A + 4 * s)) = make_float4(e0 * rs, e1 * rs, e2 * rs, e3 * rs);
        __syncthreads();

        int w = s >> 4, d = s & 15;
        float t0 = 0, t1 = 0, t2 = 0, t3 = 0;
        #pragma unroll
        for (int dp = 0; dp < DDD; ++dp) {
            float dd = (float)(d - dp);
            float k = EXP2(-dd * dd * C18);
            const float4 v = *((const float4*)(A + 4 * (w * 16 + dp)));
            t0 = fmaf(k, v.x, t0); t1 = fmaf(k, v.y, t1);
            t2 = fmaf(k, v.z, t2); t3 = fmaf(k, v.w, t3);
        }
        *((float4*)(B + 4 * s)) = make_float4(t0, t1, t2, t3);
        __syncthreads();

        float u0 = 0, u1 = 0, u2 = 0, u3 = 0;
        #pragma unroll
        for (int wp = 0; wp < WW; ++wp) {
            float dw = (float)(w - wp);
            float k = EXP2(-dw * dw * C18);
            const float4 v = *((const float4*)(B + 4 * (wp * 16 + d)));
            u0 = fmaf(k, v.x, u0); u1 = fmaf(k, v.y, u1);
            u2 = fmaf(k, v.z, u2); u3 = fmaf(k, v.w, u3);
        }
        *((float4*)(tmp + 4 * i)) = make_float4(u0, u1, u2, u3);
    }
}

// 512 blocks x 256 thr. Block owns 64 idx (= 16 i x 4 c).
// Wave q sums part slices [q*32, q*32+32) (coalesced, unrolled) + 8 hp of h-conv.
// LDS combine; threads 0..15 finish: normalize + 4x4 matmuls + unary add.
__global__ __launch_bounds__(256) void reduce_finish(
    const float* __restrict__ part,  // [KS][N*4]
    const float* __restrict__ tmp,   // [N][4] d,w-convolved softmax
    const float* __restrict__ u,
    const float* __restrict__ sk, const float* __restrict__ bk,
    const float* __restrict__ cm,
    float* __restrict__ qout)
{
    int tid = threadIdx.x;
    int q = tid >> 6;                // wave 0..3
    int lane = tid & 63;
    int idx = blockIdx.x * 64 + lane;

    float bl = 0.0f;
    #pragma unroll
    for (int k = 0; k < KS / 4; ++k)
        bl += part[(size_t)(q * (KS / 4) + k) * (NN * 4) + idx];

    int i = idx >> 2;
    int h = i >> 8;
    int scid = idx & 1023;
    float sp = 0.0f;
    #pragma unroll
    for (int k = 0; k < 8; ++k) {
        int hp = q * 8 + k;
        float dh = (float)(h - hp);
        float kk = EXP2(-dh * dh * C18);
        sp = fmaf(kk, tmp[hp * 1024 + scid], sp);
    }

    __shared__ float Lb[4][64];
    __shared__ float Ls[4][64];
    Lb[q][lane] = bl;
    Ls[q][lane] = sp;
    __syncthreads();

    if (tid < 16) {
        float b4[4], s4[4];
        #pragma unroll
        for (int c = 0; c < 4; ++c) {
            int l = tid * 4 + c;
            b4[c] = Lb[0][l] + Lb[1][l] + Lb[2][l] + Lb[3][l];
            s4[c] = Ls[0][l] + Ls[1][l] + Ls[2][l] + Ls[3][l];
        }
        float rb = 1.0f / (b4[0] + b4[1] + b4[2] + b4[3]);
        float rs = 1.0f / (s4[0] + s4[1] + s4[2] + s4[3]);
        float bo[4], so[4];
        #pragma unroll
        for (int c = 0; c < 4; ++c) { bo[c] = b4[c] * rb; so[c] = s4[c] * rs; }
        float msg[4];
        #pragma unroll
        for (int c = 0; c < 4; ++c) {
            float m = 0.0f;
            #pragma unroll
            for (int d = 0; d < 4; ++d)
                m += sk[c * 4 + d] * so[d] + bk[c * 4 + d] * bo[d];
            msg[c] = m;
        }
        int ig = blockIdx.x * 16 + tid;
        #pragma unroll
        for (int c = 0; c < 4; ++c) {
            float pw = 0.0f;
            #pragma unroll
            for (int d = 0; d < 4; ++d) pw += cm[c * 4 + d] * msg[d];
            qout[4 * ig + c] = u[4 * ig + c] + pw;
        }
    }
}

extern "C" void kernel_launch(void* const* d_in, const int* in_sizes, int n_in,
                              void* d_out, int out_size, void* d_ws, size_t ws_size,
                              hipStream_t stream)
{
    const float* u   = (const float*)d_in[0];
    const float* rgb = (const float*)d_in[1];
    const float* sk  = (const float*)d_in[2];
    const float* bk  = (const float*)d_in[3];
    const float* cm  = (const float*)d_in[4];
    float* out = (float*)d_out;

    // workspace: part[KS][N*4] (16 MB) | tmp[N][4] | qbuf[N][4]
    float* part = (float*)d_ws;
    float* tmpP = part + (size_t)KS * NN * 4;
    float* qbuf = tmpP + (size_t)NN * 4;

    dim3 blk(256);
    dim3 gF(GB + HH);            // 2048 bilat + 32 conv blocks
    dim3 gR(NN * 4 / 64);        // 512

    // iteration 1 (q = u)
    fused_bilat_conv<<<gF, blk, 0, stream>>>(u, rgb, part, tmpP);
    reduce_finish<<<gR, blk, 0, stream>>>(part, tmpP, u, sk, bk, cm, qbuf);
    // iteration 2
    fused_bilat_conv<<<gF, blk, 0, stream>>>(qbuf, rgb, part, tmpP);
    reduce_finish<<<gR, blk, 0, stream>>>(part, tmpP, u, sk, bk, cm, out);
}